// Round 5
// baseline (794.230 us; speedup 1.0000x reference)
//
#include <hip/hip_runtime.h>
#include <cstdint>

#define S_ELEMS 2097152ull   // B*T*N = 16*2048*64
#define TT 2048
#define NN 64

__device__ __forceinline__ float gelu_f(float x) {
  float x2 = x * x;
  float z = -1.5957691216057308f * x * (1.0f + 0.044715f * x2);
  return __fdividef(x, 1.0f + __expf(z));
}

__device__ __forceinline__ float2 cmul(float2 a, float2 b) {
  return make_float2(a.x * b.x - a.y * b.y, a.x * b.y + a.y * b.x);
}

// ---------------------------------------------------------------------------
// Kernel 1: warm_start_fill. 256 blocks x 256 thr. (unchanged from round 4)
// ---------------------------------------------------------------------------
__global__ __launch_bounds__(256) void fill_kernel(
    const float* __restrict__ x, const float* __restrict__ mask,
    float* __restrict__ seed_out, float* __restrict__ xsT)
{
  __shared__ float s_last[64][4], s_vfirst[64][4];
  __shared__ int   s_has[64][4], s_fidx[64][4];
  __shared__ float s_cl[64][4], s_bv[64][4];
  __shared__ int   s_ch[64][4], s_bh[64][4];
  __shared__ int   s_fg[4];

  const int tid = threadIdx.x;
  const int s4 = tid & 3, c = tid >> 2;
  const int b = blockIdx.x >> 4;
  const int n = ((blockIdx.x & 15) << 2) + s4;
  const size_t base = (size_t)b * (TT * NN) + n;
  const int t0 = c << 5;

  float ff[32];
  float last = 0.f; int has = 0; int fidx = TT; float vfirst = 0.f;
  #pragma unroll
  for (int i = 0; i < 32; ++i) {
    size_t off = base + (size_t)(t0 + i) * NN;
    float v = x[off];
    float m = mask[off];
    bool obs = (m == 0.0f);
    if (obs) { last = v; if (!has) { has = 1; fidx = t0 + i; vfirst = v; } }
    ff[i] = obs ? v : last;
  }
  s_last[c][s4] = last; s_has[c][s4] = has;
  s_vfirst[c][s4] = vfirst; s_fidx[c][s4] = fidx;
  __syncthreads();

  if (tid < 4) {
    float cl = 0.f; int ch = 0; int fg = TT;
    for (int cc = 0; cc < 64; ++cc) {
      s_cl[cc][tid] = cl; s_ch[cc][tid] = ch;
      if (s_has[cc][tid]) {
        cl = s_last[cc][tid]; ch = 1;
        if (fg == TT) fg = s_fidx[cc][tid];
      }
    }
    s_fg[tid] = fg;
    float bv = 0.f; int bh = 0;
    for (int cc = 63; cc >= 0; --cc) {
      s_bv[cc][tid] = bv; s_bh[cc][tid] = bh;
      if (s_has[cc][tid]) { bv = s_vfirst[cc][tid]; bh = 1; }
    }
  }
  __syncthreads();

  const float cl  = s_cl[c][s4]; const int ch  = s_ch[c][s4];
  const float bcv = s_bv[c][s4]; const int bch = s_bh[c][s4];
  const int firstg = s_fg[s4];
  const float pre = ch ? cl : 0.f;
  const int floc = fidx - t0;
  const size_t tbase = ((size_t)b * NN + n) * TT;

  float lastb = 0.f; int hasb = 0;
  float xb0, xb1, xb2, xb3;
  #pragma unroll
  for (int i = 31; i >= 0; --i) {
    int t = t0 + i;
    size_t off = base + (size_t)t * NN;
    float v = x[off];
    float m = mask[off];
    bool obs = (m == 0.0f);
    if (obs) { lastb = v; hasb = 1; }
    float bf = hasb ? lastb : bcv;
    int bav = hasb | bch;
    float ffv = (i < floc) ? pre : ff[i];
    int fav = (t >= firstg) ? 1 : 0;
    float sv;
    if (obs) sv = v;
    else if (fav && bav) sv = 0.5f * (ffv + bf);
    else if (fav) sv = ffv;
    else if (bav) sv = bf;
    else sv = 0.f;
    seed_out[off] = sv;
    if ((i & 3) == 3) xb3 = sv;
    else if ((i & 3) == 2) xb2 = sv;
    else if ((i & 3) == 1) xb1 = sv;
    else {
      xb0 = sv;
      *(float4*)(xsT + tbase + t) = make_float4(xb0, xb1, xb2, xb3);
    }
  }
}

// ---------------------------------------------------------------------------
// Kernel 2: adjacency + filter transpose. (unchanged from round 4)
// ---------------------------------------------------------------------------
__global__ __launch_bounds__(256) void adj_prep_kernel(
    const float* __restrict__ node_emb,
    const float* __restrict__ fre, const float* __restrict__ fim,
    float* __restrict__ adj, float2* __restrict__ filtT)
{
  const int tid = threadIdx.x;
  if (blockIdx.x == 0) {
    __shared__ float E[64 * 32];
    for (int i = tid; i < 2048; i += 256) E[i] = node_emb[i];
    __syncthreads();
    if (tid < 64) {
      float er[32];
      #pragma unroll
      for (int k = 0; k < 32; ++k) er[k] = E[tid * 32 + k];
      float sc[64];
      float mx = -1e30f;
      #pragma unroll
      for (int j = 0; j < 64; ++j) {
        float acc = 0.f;
        #pragma unroll
        for (int k = 0; k < 32; ++k) acc += er[k] * E[j * 32 + k];
        acc = fmaxf(acc, 0.f);
        sc[j] = acc;
        mx = fmaxf(mx, acc);
      }
      float sum = 0.f;
      #pragma unroll
      for (int j = 0; j < 64; ++j) { float e = __expf(sc[j] - mx); sc[j] = e; sum += e; }
      float inv = __fdividef(1.f, sum);
      #pragma unroll
      for (int j = 0; j < 64; ++j) adj[tid * 64 + j] = sc[j] * inv;
    }
  } else {
    for (int idx = (blockIdx.x - 1) * 256 + tid; idx < 1025 * 64; idx += 5 * 256) {
      int k = idx >> 6, nn = idx & 63;
      filtT[(size_t)nn * 1025 + k] = make_float2(fre[idx], fim[idx]);
    }
  }
}

// ---------------------------------------------------------------------------
// Kernel 3: x_gcn, 32 rows/block. (unchanged from round 4)
// ---------------------------------------------------------------------------
__global__ __launch_bounds__(256) void gcn_kernel(
    const float* __restrict__ seed, const float* __restrict__ adj,
    const float* __restrict__ w1, const float* __restrict__ b1,
    const float* __restrict__ w2, const float* __restrict__ b2p,
    float* __restrict__ xgcn)
{
  __shared__ float At[64 * 65];
  __shared__ float su[4][64];
  __shared__ float sw1[32], sb1[32], sw2[32];
  const int tid = threadIdx.x;
  for (int i = tid; i < 4096; i += 256) {
    int nn = i >> 6, m = i & 63;
    At[m * 65 + nn] = adj[i];
  }
  if (tid < 32) { sw1[tid] = w1[tid]; sb1[tid] = b1[tid]; sw2[tid] = w2[tid]; }
  const float b2 = b2p[0];
  const int r = tid >> 6, n = tid & 63;
  const size_t row0 = (size_t)blockIdx.x * 32;

  for (int it = 0; it < 8; ++it) {
    __syncthreads();
    size_t row = row0 + it * 4 + r;
    float xv = seed[row * 64 + n];
    float u = 0.f;
    #pragma unroll
    for (int h = 0; h < 32; ++h) u += sw2[h] * gelu_f(xv * sw1[h] + sb1[h]);
    su[r][n] = u;
    __syncthreads();
    float acc = b2;
    #pragma unroll 16
    for (int m = 0; m < 64; ++m) acc += At[m * 65 + n] * su[r][m];
    xgcn[row * 64 + n] = acc;
  }
}

// ---------------------------------------------------------------------------
// Kernel 4: FFT filter, radix-4. (unchanged from round 4)
// ---------------------------------------------------------------------------
__global__ __launch_bounds__(256) void fft_kernel(
    const float* __restrict__ xsT, const float2* __restrict__ filtT,
    float* __restrict__ xfreq)
{
  __shared__ float2 D[2048];
  __shared__ float2 TW[1024];
  __shared__ float2 FL[1025];
  const int tid = threadIdx.x;
  const int series = blockIdx.x;
  const int bb = series >> 6, n = series & 63;

  for (int m = tid; m < 1024; m += 256) {
    float s, c;
    __sincosf(-3.0679615757712823e-3f * (float)m, &s, &c);  // -2*pi*m/2048
    TW[m] = make_float2(c, s);
  }
  {
    const float2* fsrc = filtT + (size_t)n * 1025;
    for (int i = tid; i < 1025; i += 256) FL[i] = fsrc[i];
  }
  const float* src = xsT + (size_t)series * TT;
  for (int i = tid; i < TT; i += 256) D[i] = make_float2(src[i], 0.f);
  __syncthreads();

  #pragma unroll
  for (int lh = 9; lh >= 1; lh -= 2) {
    const int h = 1 << lh;
    const int tstr = 512 >> lh;
    #pragma unroll
    for (int w = 0; w < 2; ++w) {
      const int u = tid + (w << 8);
      const int j = u & (h - 1);
      const int p = ((u >> lh) << (lh + 2)) + j;
      float2 x0 = D[p], x1 = D[p + h], x2 = D[p + 2 * h], x3 = D[p + 3 * h];
      float2 W  = TW[j * tstr];
      float2 W2 = TW[2 * j * tstr];
      float2 W3 = cmul(W, W2);
      float2 s02 = make_float2(x0.x + x2.x, x0.y + x2.y);
      float2 d02 = make_float2(x0.x - x2.x, x0.y - x2.y);
      float2 s13 = make_float2(x1.x + x3.x, x1.y + x3.y);
      float2 d13 = make_float2(x1.x - x3.x, x1.y - x3.y);
      D[p]         = make_float2(s02.x + s13.x, s02.y + s13.y);
      D[p + h]     = cmul(make_float2(s02.x - s13.x, s02.y - s13.y), W2);
      D[p + 2 * h] = cmul(make_float2(d02.x + d13.y, d02.y - d13.x), W);
      D[p + 3 * h] = cmul(make_float2(d02.x - d13.y, d02.y + d13.x), W3);
    }
    __syncthreads();
  }
  #pragma unroll
  for (int w = 0; w < 4; ++w) {
    const int u = tid + (w << 8);
    const int p = u * 2;
    float2 a = D[p], b = D[p + 1];
    D[p]     = make_float2(a.x + b.x, a.y + b.y);
    D[p + 1] = make_float2(a.x - b.x, a.y - b.y);
  }
  __syncthreads();

  for (int p = tid; p < TT; p += 256) {
    const int k = (int)(__brev((unsigned)p) >> 21);
    float2 f;
    if (k <= 1024) f = FL[k];
    else { f = FL[2048 - k]; f.y = -f.y; }
    float2 Xv = D[p];
    float pr = Xv.x * f.x - Xv.y * f.y;
    float pi = Xv.x * f.y + Xv.y * f.x;
    if (k == 0 || k == 1024) pi = 0.f;
    D[p] = make_float2(pr, pi);
  }
  __syncthreads();

  #pragma unroll
  for (int w = 0; w < 4; ++w) {
    const int u = tid + (w << 8);
    const int p = u * 2;
    float2 a = D[p], b = D[p + 1];
    D[p]     = make_float2(a.x + b.x, a.y + b.y);
    D[p + 1] = make_float2(a.x - b.x, a.y - b.y);
  }
  __syncthreads();
  #pragma unroll
  for (int lh = 1; lh <= 9; lh += 2) {
    const int h = 1 << lh;
    const int tstr = 512 >> lh;
    #pragma unroll
    for (int w = 0; w < 2; ++w) {
      const int u = tid + (w << 8);
      const int j = u & (h - 1);
      const int p = ((u >> lh) << (lh + 2)) + j;
      float2 z0 = D[p], z1 = D[p + h], z2 = D[p + 2 * h], z3 = D[p + 3 * h];
      float2 W  = TW[j * tstr];
      float2 W2 = TW[2 * j * tstr];
      float2 cW  = make_float2(W.x, -W.y);
      float2 cW2 = make_float2(W2.x, -W2.y);
      float2 icW = make_float2(-cW.y, cW.x);
      float2 t1 = cmul(z1, cW2);
      float2 y0 = make_float2(z0.x + t1.x, z0.y + t1.y);
      float2 y1 = make_float2(z0.x - t1.x, z0.y - t1.y);
      float2 t3 = cmul(z3, cW2);
      float2 y2 = make_float2(z2.x + t3.x, z2.y + t3.y);
      float2 y3 = make_float2(z2.x - t3.x, z2.y - t3.y);
      float2 u2 = cmul(y2, cW);
      float2 u3 = cmul(y3, icW);
      D[p]         = make_float2(y0.x + u2.x, y0.y + u2.y);
      D[p + 2 * h] = make_float2(y0.x - u2.x, y0.y - u2.y);
      D[p + h]     = make_float2(y1.x + u3.x, y1.y + u3.y);
      D[p + 3 * h] = make_float2(y1.x - u3.x, y1.y - u3.y);
    }
    __syncthreads();
  }

  const float inv = (1.0f / 2048.0f);
  const size_t obase = (size_t)bb * (TT * NN) + n;
  for (int t2 = tid; t2 < TT; t2 += 256) {
    xfreq[obase + (size_t)t2 * NN] = D[t2].x * inv;
  }
}

// ---------------------------------------------------------------------------
// Kernel 5: gate MLP. Accumulators are 16 NAMED float4 values (no array) so
// the allocator cannot demote them to scratch (round-4 regression: identical
// source with float4 a2[16] compiled to a 60-VGPR + scratch body, 546us).
// ---------------------------------------------------------------------------
__global__ __launch_bounds__(256) void mlp_kernel(
    const float* __restrict__ xin, const float* __restrict__ mask, const int* __restrict__ rate_id,
    const float* __restrict__ rate_table,
    const float* __restrict__ gw1, const float* __restrict__ gb1,
    const float* __restrict__ gw2, const float* __restrict__ gb2,
    const float* __restrict__ gw3, const float* __restrict__ gb3,
    float* __restrict__ out)
{
  __shared__ __align__(16) float s_gw2[4096];
  __shared__ __align__(16) float s_l1[512];
  __shared__ __align__(16) float s_b1rT[512];
  __shared__ __align__(16) float s_w3d[64];
  __shared__ __align__(16) float s_gb2[64];
  __shared__ int s_rid[64];
  const int tid = threadIdx.x;
  for (int i = tid; i < 4096; i += 256) s_gw2[i] = gw2[i];
  for (int i = tid; i < 512; i += 256) {
    int k = i >> 3, c = i & 7;
    s_l1[i] = (c < 6) ? gw1[c * 64 + k] : 0.f;
  }
  for (int i = tid; i < 512; i += 256) {
    int k = i >> 3, r = i & 7;
    float acc = gb1[k];
    #pragma unroll
    for (int e = 0; e < 16; ++e) acc += rate_table[r * 16 + e] * gw1[(6 + e) * 64 + k];
    s_b1rT[i] = acc;
  }
  if (tid < 64) {
    s_w3d[tid] = gw3[tid * 2] - gw3[tid * 2 + 1];
    s_gb2[tid] = gb2[tid];
    s_rid[tid] = rate_id[tid];
  }
  __syncthreads();

  const size_t idx = (size_t)blockIdx.x * 256 + tid;
  const float seed = out[idx];
  const float gcn  = out[S_ELEMS + idx];
  const float freq = out[2 * S_ELEMS + idx];
  const float mk = mask[idx];
  const int rid = s_rid[tid & 63];
  const float f0 = seed, f1 = mk, f2 = gcn, f3 = freq, f4 = gcn - seed, f5 = freq - seed;

  const float4* gb2v = (const float4*)s_gb2;
  float4 a2_0  = gb2v[0],  a2_1  = gb2v[1],  a2_2  = gb2v[2],  a2_3  = gb2v[3];
  float4 a2_4  = gb2v[4],  a2_5  = gb2v[5],  a2_6  = gb2v[6],  a2_7  = gb2v[7];
  float4 a2_8  = gb2v[8],  a2_9  = gb2v[9],  a2_10 = gb2v[10], a2_11 = gb2v[11];
  float4 a2_12 = gb2v[12], a2_13 = gb2v[13], a2_14 = gb2v[14], a2_15 = gb2v[15];

  const float4* l1v = (const float4*)s_l1;
  const float4* w2v = (const float4*)s_gw2;

#define Q_UPDATE(q) { float4 w = w2v[k * 16 + q]; \
    a2_##q.x += ak * w.x; a2_##q.y += ak * w.y; \
    a2_##q.z += ak * w.z; a2_##q.w += ak * w.w; }

  #pragma unroll 2
  for (int k = 0; k < 64; ++k) {
    float4 wA = l1v[k * 2], wB = l1v[k * 2 + 1];
    float pre = s_b1rT[k * 8 + rid];
    float a = pre + wA.x * f0 + wA.y * f1 + wA.z * f2 + wA.w * f3 + wB.x * f4 + wB.y * f5;
    float ak = gelu_f(a);
    Q_UPDATE(0)  Q_UPDATE(1)  Q_UPDATE(2)  Q_UPDATE(3)
    Q_UPDATE(4)  Q_UPDATE(5)  Q_UPDATE(6)  Q_UPDATE(7)
    Q_UPDATE(8)  Q_UPDATE(9)  Q_UPDATE(10) Q_UPDATE(11)
    Q_UPDATE(12) Q_UPDATE(13) Q_UPDATE(14) Q_UPDATE(15)
  }
#undef Q_UPDATE

  float d = gb3[0] - gb3[1];
  const float4* w3v = (const float4*)s_w3d;
#define Q_FINAL(q) { float4 w = w3v[q]; \
    d += gelu_f(a2_##q.x) * w.x + gelu_f(a2_##q.y) * w.y \
       + gelu_f(a2_##q.z) * w.z + gelu_f(a2_##q.w) * w.w; }
  Q_FINAL(0)  Q_FINAL(1)  Q_FINAL(2)  Q_FINAL(3)
  Q_FINAL(4)  Q_FINAL(5)  Q_FINAL(6)  Q_FINAL(7)
  Q_FINAL(8)  Q_FINAL(9)  Q_FINAL(10) Q_FINAL(11)
  Q_FINAL(12) Q_FINAL(13) Q_FINAL(14) Q_FINAL(15)
#undef Q_FINAL

  float w0 = __fdividef(1.0f, 1.0f + __expf(-d));
  float w1g = 1.0f - w0;
  float ximp = w0 * gcn + w1g * freq;
  float xcmp = (mk != 0.0f) ? ximp : xin[idx];
  out[3 * S_ELEMS + idx] = ximp;
  out[4 * S_ELEMS + idx] = xcmp;
  ((float2*)(out + 5 * S_ELEMS))[idx] = make_float2(w0, w1g);
}

// ---------------------------------------------------------------------------
extern "C" void kernel_launch(void* const* d_in, const int* in_sizes, int n_in,
                              void* d_out, int out_size, void* d_ws, size_t ws_size,
                              hipStream_t stream) {
  (void)in_sizes; (void)n_in; (void)out_size; (void)d_ws; (void)ws_size;
  const float* x_input    = (const float*)d_in[0];
  const float* mask       = (const float*)d_in[1];
  const int*   rate_id    = (const int*)d_in[2];
  const float* node_emb   = (const float*)d_in[3];
  const float* gcn_w1     = (const float*)d_in[4];
  const float* gcn_b1     = (const float*)d_in[5];
  const float* gcn_w2     = (const float*)d_in[6];
  const float* gcn_b2     = (const float*)d_in[7];
  const float* freq_re    = (const float*)d_in[8];
  const float* freq_im    = (const float*)d_in[9];
  const float* rate_table = (const float*)d_in[10];
  const float* gw1        = (const float*)d_in[11];
  const float* gb1        = (const float*)d_in[12];
  const float* gw2        = (const float*)d_in[13];
  const float* gb2        = (const float*)d_in[14];
  const float* gw3        = (const float*)d_in[15];
  const float* gb3        = (const float*)d_in[16];
  float* out = (float*)d_out;

  float* out0 = out;                 // x_seed
  float* out1 = out + S_ELEMS;       // x_gcn
  float* out2 = out + 2 * S_ELEMS;   // x_freq
  float* out4 = out + 4 * S_ELEMS;   // scratch (seed^T) -> x_complete (mlp)
  float* out6 = out + 7 * S_ELEMS;   // adjacency
  float2* filtT = (float2*)(out + 5 * S_ELEMS);  // scratch -> gate weights (mlp)

  fill_kernel<<<256, 256, 0, stream>>>(x_input, mask, out0, out4);
  adj_prep_kernel<<<6, 256, 0, stream>>>(node_emb, freq_re, freq_im, out6, filtT);
  gcn_kernel<<<1024, 256, 0, stream>>>(out0, out6, gcn_w1, gcn_b1, gcn_w2, gcn_b2, out1);
  fft_kernel<<<1024, 256, 0, stream>>>(out4, filtT, out2);
  mlp_kernel<<<8192, 256, 0, stream>>>(x_input, mask, rate_id, rate_table,
                                       gw1, gb1, gw2, gb2, gw3, gb3, out);
}

// Round 6
// 715.645 us; speedup vs baseline: 1.1098x; 1.1098x over previous
//
#include <hip/hip_runtime.h>
#include <cstdint>

#define S_ELEMS 2097152ull   // B*T*N = 16*2048*64
#define TT 2048
#define NN 64

__device__ __forceinline__ float gelu_f(float x) {
  float x2 = x * x;
  float z = -1.5957691216057308f * x * (1.0f + 0.044715f * x2);
  return __fdividef(x, 1.0f + __expf(z));
}

__device__ __forceinline__ float2 cmul(float2 a, float2 b) {
  return make_float2(a.x * b.x - a.y * b.y, a.x * b.y + a.y * b.x);
}

// ---------------------------------------------------------------------------
// Kernel 1: warm_start_fill. 256 blocks x 256 thr. (unchanged)
// ---------------------------------------------------------------------------
__global__ __launch_bounds__(256) void fill_kernel(
    const float* __restrict__ x, const float* __restrict__ mask,
    float* __restrict__ seed_out, float* __restrict__ xsT)
{
  __shared__ float s_last[64][4], s_vfirst[64][4];
  __shared__ int   s_has[64][4], s_fidx[64][4];
  __shared__ float s_cl[64][4], s_bv[64][4];
  __shared__ int   s_ch[64][4], s_bh[64][4];
  __shared__ int   s_fg[4];

  const int tid = threadIdx.x;
  const int s4 = tid & 3, c = tid >> 2;
  const int b = blockIdx.x >> 4;
  const int n = ((blockIdx.x & 15) << 2) + s4;
  const size_t base = (size_t)b * (TT * NN) + n;
  const int t0 = c << 5;

  float ff[32];
  float last = 0.f; int has = 0; int fidx = TT; float vfirst = 0.f;
  #pragma unroll
  for (int i = 0; i < 32; ++i) {
    size_t off = base + (size_t)(t0 + i) * NN;
    float v = x[off];
    float m = mask[off];
    bool obs = (m == 0.0f);
    if (obs) { last = v; if (!has) { has = 1; fidx = t0 + i; vfirst = v; } }
    ff[i] = obs ? v : last;
  }
  s_last[c][s4] = last; s_has[c][s4] = has;
  s_vfirst[c][s4] = vfirst; s_fidx[c][s4] = fidx;
  __syncthreads();

  if (tid < 4) {
    float cl = 0.f; int ch = 0; int fg = TT;
    for (int cc = 0; cc < 64; ++cc) {
      s_cl[cc][tid] = cl; s_ch[cc][tid] = ch;
      if (s_has[cc][tid]) {
        cl = s_last[cc][tid]; ch = 1;
        if (fg == TT) fg = s_fidx[cc][tid];
      }
    }
    s_fg[tid] = fg;
    float bv = 0.f; int bh = 0;
    for (int cc = 63; cc >= 0; --cc) {
      s_bv[cc][tid] = bv; s_bh[cc][tid] = bh;
      if (s_has[cc][tid]) { bv = s_vfirst[cc][tid]; bh = 1; }
    }
  }
  __syncthreads();

  const float cl  = s_cl[c][s4]; const int ch  = s_ch[c][s4];
  const float bcv = s_bv[c][s4]; const int bch = s_bh[c][s4];
  const int firstg = s_fg[s4];
  const float pre = ch ? cl : 0.f;
  const int floc = fidx - t0;
  const size_t tbase = ((size_t)b * NN + n) * TT;

  float lastb = 0.f; int hasb = 0;
  float xb0, xb1, xb2, xb3;
  #pragma unroll
  for (int i = 31; i >= 0; --i) {
    int t = t0 + i;
    size_t off = base + (size_t)t * NN;
    float v = x[off];
    float m = mask[off];
    bool obs = (m == 0.0f);
    if (obs) { lastb = v; hasb = 1; }
    float bf = hasb ? lastb : bcv;
    int bav = hasb | bch;
    float ffv = (i < floc) ? pre : ff[i];
    int fav = (t >= firstg) ? 1 : 0;
    float sv;
    if (obs) sv = v;
    else if (fav && bav) sv = 0.5f * (ffv + bf);
    else if (fav) sv = ffv;
    else if (bav) sv = bf;
    else sv = 0.f;
    seed_out[off] = sv;
    if ((i & 3) == 3) xb3 = sv;
    else if ((i & 3) == 2) xb2 = sv;
    else if ((i & 3) == 1) xb1 = sv;
    else {
      xb0 = sv;
      *(float4*)(xsT + tbase + t) = make_float4(xb0, xb1, xb2, xb3);
    }
  }
}

// ---------------------------------------------------------------------------
// Kernel 2: adjacency + filter transpose. (unchanged)
// ---------------------------------------------------------------------------
__global__ __launch_bounds__(256) void adj_prep_kernel(
    const float* __restrict__ node_emb,
    const float* __restrict__ fre, const float* __restrict__ fim,
    float* __restrict__ adj, float2* __restrict__ filtT)
{
  const int tid = threadIdx.x;
  if (blockIdx.x == 0) {
    __shared__ float E[64 * 32];
    for (int i = tid; i < 2048; i += 256) E[i] = node_emb[i];
    __syncthreads();
    if (tid < 64) {
      float er[32];
      #pragma unroll
      for (int k = 0; k < 32; ++k) er[k] = E[tid * 32 + k];
      float sc[64];
      float mx = -1e30f;
      #pragma unroll
      for (int j = 0; j < 64; ++j) {
        float acc = 0.f;
        #pragma unroll
        for (int k = 0; k < 32; ++k) acc += er[k] * E[j * 32 + k];
        acc = fmaxf(acc, 0.f);
        sc[j] = acc;
        mx = fmaxf(mx, acc);
      }
      float sum = 0.f;
      #pragma unroll
      for (int j = 0; j < 64; ++j) { float e = __expf(sc[j] - mx); sc[j] = e; sum += e; }
      float inv = __fdividef(1.f, sum);
      #pragma unroll
      for (int j = 0; j < 64; ++j) adj[tid * 64 + j] = sc[j] * inv;
    }
  } else {
    for (int idx = (blockIdx.x - 1) * 256 + tid; idx < 1025 * 64; idx += 5 * 256) {
      int k = idx >> 6, nn = idx & 63;
      filtT[(size_t)nn * 1025 + k] = make_float2(fre[idx], fim[idx]);
    }
  }
}

// ---------------------------------------------------------------------------
// Kernel 3: x_gcn, 32 rows/block. (unchanged)
// ---------------------------------------------------------------------------
__global__ __launch_bounds__(256) void gcn_kernel(
    const float* __restrict__ seed, const float* __restrict__ adj,
    const float* __restrict__ w1, const float* __restrict__ b1,
    const float* __restrict__ w2, const float* __restrict__ b2p,
    float* __restrict__ xgcn)
{
  __shared__ float At[64 * 65];
  __shared__ float su[4][64];
  __shared__ float sw1[32], sb1[32], sw2[32];
  const int tid = threadIdx.x;
  for (int i = tid; i < 4096; i += 256) {
    int nn = i >> 6, m = i & 63;
    At[m * 65 + nn] = adj[i];
  }
  if (tid < 32) { sw1[tid] = w1[tid]; sb1[tid] = b1[tid]; sw2[tid] = w2[tid]; }
  const float b2 = b2p[0];
  const int r = tid >> 6, n = tid & 63;
  const size_t row0 = (size_t)blockIdx.x * 32;

  for (int it = 0; it < 8; ++it) {
    __syncthreads();
    size_t row = row0 + it * 4 + r;
    float xv = seed[row * 64 + n];
    float u = 0.f;
    #pragma unroll
    for (int h = 0; h < 32; ++h) u += sw2[h] * gelu_f(xv * sw1[h] + sb1[h]);
    su[r][n] = u;
    __syncthreads();
    float acc = b2;
    #pragma unroll 16
    for (int m = 0; m < 64; ++m) acc += At[m * 65 + n] * su[r][m];
    xgcn[row * 64 + n] = acc;
  }
}

// ---------------------------------------------------------------------------
// Kernel 4: FFT filter, radix-4. (unchanged)
// ---------------------------------------------------------------------------
__global__ __launch_bounds__(256) void fft_kernel(
    const float* __restrict__ xsT, const float2* __restrict__ filtT,
    float* __restrict__ xfreq)
{
  __shared__ float2 D[2048];
  __shared__ float2 TW[1024];
  __shared__ float2 FL[1025];
  const int tid = threadIdx.x;
  const int series = blockIdx.x;
  const int bb = series >> 6, n = series & 63;

  for (int m = tid; m < 1024; m += 256) {
    float s, c;
    __sincosf(-3.0679615757712823e-3f * (float)m, &s, &c);  // -2*pi*m/2048
    TW[m] = make_float2(c, s);
  }
  {
    const float2* fsrc = filtT + (size_t)n * 1025;
    for (int i = tid; i < 1025; i += 256) FL[i] = fsrc[i];
  }
  const float* src = xsT + (size_t)series * TT;
  for (int i = tid; i < TT; i += 256) D[i] = make_float2(src[i], 0.f);
  __syncthreads();

  #pragma unroll
  for (int lh = 9; lh >= 1; lh -= 2) {
    const int h = 1 << lh;
    const int tstr = 512 >> lh;
    #pragma unroll
    for (int w = 0; w < 2; ++w) {
      const int u = tid + (w << 8);
      const int j = u & (h - 1);
      const int p = ((u >> lh) << (lh + 2)) + j;
      float2 x0 = D[p], x1 = D[p + h], x2 = D[p + 2 * h], x3 = D[p + 3 * h];
      float2 W  = TW[j * tstr];
      float2 W2 = TW[2 * j * tstr];
      float2 W3 = cmul(W, W2);
      float2 s02 = make_float2(x0.x + x2.x, x0.y + x2.y);
      float2 d02 = make_float2(x0.x - x2.x, x0.y - x2.y);
      float2 s13 = make_float2(x1.x + x3.x, x1.y + x3.y);
      float2 d13 = make_float2(x1.x - x3.x, x1.y - x3.y);
      D[p]         = make_float2(s02.x + s13.x, s02.y + s13.y);
      D[p + h]     = cmul(make_float2(s02.x - s13.x, s02.y - s13.y), W2);
      D[p + 2 * h] = cmul(make_float2(d02.x + d13.y, d02.y - d13.x), W);
      D[p + 3 * h] = cmul(make_float2(d02.x - d13.y, d02.y + d13.x), W3);
    }
    __syncthreads();
  }
  #pragma unroll
  for (int w = 0; w < 4; ++w) {
    const int u = tid + (w << 8);
    const int p = u * 2;
    float2 a = D[p], b = D[p + 1];
    D[p]     = make_float2(a.x + b.x, a.y + b.y);
    D[p + 1] = make_float2(a.x - b.x, a.y - b.y);
  }
  __syncthreads();

  for (int p = tid; p < TT; p += 256) {
    const int k = (int)(__brev((unsigned)p) >> 21);
    float2 f;
    if (k <= 1024) f = FL[k];
    else { f = FL[2048 - k]; f.y = -f.y; }
    float2 Xv = D[p];
    float pr = Xv.x * f.x - Xv.y * f.y;
    float pi = Xv.x * f.y + Xv.y * f.x;
    if (k == 0 || k == 1024) pi = 0.f;
    D[p] = make_float2(pr, pi);
  }
  __syncthreads();

  #pragma unroll
  for (int w = 0; w < 4; ++w) {
    const int u = tid + (w << 8);
    const int p = u * 2;
    float2 a = D[p], b = D[p + 1];
    D[p]     = make_float2(a.x + b.x, a.y + b.y);
    D[p + 1] = make_float2(a.x - b.x, a.y - b.y);
  }
  __syncthreads();
  #pragma unroll
  for (int lh = 1; lh <= 9; lh += 2) {
    const int h = 1 << lh;
    const int tstr = 512 >> lh;
    #pragma unroll
    for (int w = 0; w < 2; ++w) {
      const int u = tid + (w << 8);
      const int j = u & (h - 1);
      const int p = ((u >> lh) << (lh + 2)) + j;
      float2 z0 = D[p], z1 = D[p + h], z2 = D[p + 2 * h], z3 = D[p + 3 * h];
      float2 W  = TW[j * tstr];
      float2 W2 = TW[2 * j * tstr];
      float2 cW  = make_float2(W.x, -W.y);
      float2 cW2 = make_float2(W2.x, -W2.y);
      float2 icW = make_float2(-cW.y, cW.x);
      float2 t1 = cmul(z1, cW2);
      float2 y0 = make_float2(z0.x + t1.x, z0.y + t1.y);
      float2 y1 = make_float2(z0.x - t1.x, z0.y - t1.y);
      float2 t3 = cmul(z3, cW2);
      float2 y2 = make_float2(z2.x + t3.x, z2.y + t3.y);
      float2 y3 = make_float2(z2.x - t3.x, z2.y - t3.y);
      float2 u2 = cmul(y2, cW);
      float2 u3 = cmul(y3, icW);
      D[p]         = make_float2(y0.x + u2.x, y0.y + u2.y);
      D[p + 2 * h] = make_float2(y0.x - u2.x, y0.y - u2.y);
      D[p + h]     = make_float2(y1.x + u3.x, y1.y + u3.y);
      D[p + 3 * h] = make_float2(y1.x - u3.x, y1.y - u3.y);
    }
    __syncthreads();
  }

  const float inv = (1.0f / 2048.0f);
  const size_t obase = (size_t)bb * (TT * NN) + n;
  for (int t2 = tid; t2 < TT; t2 += 256) {
    xfreq[obase + (size_t)t2 * NN] = D[t2].x * inv;
  }
}

// ---------------------------------------------------------------------------
// Kernel 5: gate MLP. __launch_bounds__(256, 2) lifts the VGPR cap to 256
// per wave (rounds 4/5: allocator capped at 60-76 VGPRs and spilled the 64
// accumulator registers to scratch -> 546-620us). Named float4 accumulators.
// ---------------------------------------------------------------------------
__global__ __launch_bounds__(256, 2) void mlp_kernel(
    const float* __restrict__ xin, const float* __restrict__ mask, const int* __restrict__ rate_id,
    const float* __restrict__ rate_table,
    const float* __restrict__ gw1, const float* __restrict__ gb1,
    const float* __restrict__ gw2, const float* __restrict__ gb2,
    const float* __restrict__ gw3, const float* __restrict__ gb3,
    float* __restrict__ out)
{
  __shared__ __align__(16) float s_gw2[4096];
  __shared__ __align__(16) float s_l1[512];
  __shared__ __align__(16) float s_b1rT[512];
  __shared__ __align__(16) float s_w3d[64];
  __shared__ __align__(16) float s_gb2[64];
  __shared__ int s_rid[64];
  const int tid = threadIdx.x;
  for (int i = tid; i < 4096; i += 256) s_gw2[i] = gw2[i];
  for (int i = tid; i < 512; i += 256) {
    int k = i >> 3, c = i & 7;
    s_l1[i] = (c < 6) ? gw1[c * 64 + k] : 0.f;
  }
  for (int i = tid; i < 512; i += 256) {
    int k = i >> 3, r = i & 7;
    float acc = gb1[k];
    #pragma unroll
    for (int e = 0; e < 16; ++e) acc += rate_table[r * 16 + e] * gw1[(6 + e) * 64 + k];
    s_b1rT[i] = acc;
  }
  if (tid < 64) {
    s_w3d[tid] = gw3[tid * 2] - gw3[tid * 2 + 1];
    s_gb2[tid] = gb2[tid];
    s_rid[tid] = rate_id[tid];
  }
  __syncthreads();

  const size_t idx = (size_t)blockIdx.x * 256 + tid;
  const float seed = out[idx];
  const float gcn  = out[S_ELEMS + idx];
  const float freq = out[2 * S_ELEMS + idx];
  const float mk = mask[idx];
  const int rid = s_rid[tid & 63];
  const float f0 = seed, f1 = mk, f2 = gcn, f3 = freq, f4 = gcn - seed, f5 = freq - seed;

  const float4* gb2v = (const float4*)s_gb2;
  float4 a2_0  = gb2v[0],  a2_1  = gb2v[1],  a2_2  = gb2v[2],  a2_3  = gb2v[3];
  float4 a2_4  = gb2v[4],  a2_5  = gb2v[5],  a2_6  = gb2v[6],  a2_7  = gb2v[7];
  float4 a2_8  = gb2v[8],  a2_9  = gb2v[9],  a2_10 = gb2v[10], a2_11 = gb2v[11];
  float4 a2_12 = gb2v[12], a2_13 = gb2v[13], a2_14 = gb2v[14], a2_15 = gb2v[15];

  const float4* l1v = (const float4*)s_l1;
  const float4* w2v = (const float4*)s_gw2;

#define Q_UPDATE(q) { float4 w = w2v[k * 16 + q]; \
    a2_##q.x += ak * w.x; a2_##q.y += ak * w.y; \
    a2_##q.z += ak * w.z; a2_##q.w += ak * w.w; }

  #pragma unroll 4
  for (int k = 0; k < 64; ++k) {
    float4 wA = l1v[k * 2], wB = l1v[k * 2 + 1];
    float pre = s_b1rT[k * 8 + rid];
    float a = pre + wA.x * f0 + wA.y * f1 + wA.z * f2 + wA.w * f3 + wB.x * f4 + wB.y * f5;
    float ak = gelu_f(a);
    Q_UPDATE(0)  Q_UPDATE(1)  Q_UPDATE(2)  Q_UPDATE(3)
    Q_UPDATE(4)  Q_UPDATE(5)  Q_UPDATE(6)  Q_UPDATE(7)
    Q_UPDATE(8)  Q_UPDATE(9)  Q_UPDATE(10) Q_UPDATE(11)
    Q_UPDATE(12) Q_UPDATE(13) Q_UPDATE(14) Q_UPDATE(15)
  }
#undef Q_UPDATE

  float d = gb3[0] - gb3[1];
  const float4* w3v = (const float4*)s_w3d;
#define Q_FINAL(q) { float4 w = w3v[q]; \
    d += gelu_f(a2_##q.x) * w.x + gelu_f(a2_##q.y) * w.y \
       + gelu_f(a2_##q.z) * w.z + gelu_f(a2_##q.w) * w.w; }
  Q_FINAL(0)  Q_FINAL(1)  Q_FINAL(2)  Q_FINAL(3)
  Q_FINAL(4)  Q_FINAL(5)  Q_FINAL(6)  Q_FINAL(7)
  Q_FINAL(8)  Q_FINAL(9)  Q_FINAL(10) Q_FINAL(11)
  Q_FINAL(12) Q_FINAL(13) Q_FINAL(14) Q_FINAL(15)
#undef Q_FINAL

  float w0 = __fdividef(1.0f, 1.0f + __expf(-d));
  float w1g = 1.0f - w0;
  float ximp = w0 * gcn + w1g * freq;
  float xcmp = (mk != 0.0f) ? ximp : xin[idx];
  out[3 * S_ELEMS + idx] = ximp;
  out[4 * S_ELEMS + idx] = xcmp;
  ((float2*)(out + 5 * S_ELEMS))[idx] = make_float2(w0, w1g);
}

// ---------------------------------------------------------------------------
extern "C" void kernel_launch(void* const* d_in, const int* in_sizes, int n_in,
                              void* d_out, int out_size, void* d_ws, size_t ws_size,
                              hipStream_t stream) {
  (void)in_sizes; (void)n_in; (void)out_size; (void)d_ws; (void)ws_size;
  const float* x_input    = (const float*)d_in[0];
  const float* mask       = (const float*)d_in[1];
  const int*   rate_id    = (const int*)d_in[2];
  const float* node_emb   = (const float*)d_in[3];
  const float* gcn_w1     = (const float*)d_in[4];
  const float* gcn_b1     = (const float*)d_in[5];
  const float* gcn_w2     = (const float*)d_in[6];
  const float* gcn_b2     = (const float*)d_in[7];
  const float* freq_re    = (const float*)d_in[8];
  const float* freq_im    = (const float*)d_in[9];
  const float* rate_table = (const float*)d_in[10];
  const float* gw1        = (const float*)d_in[11];
  const float* gb1        = (const float*)d_in[12];
  const float* gw2        = (const float*)d_in[13];
  const float* gb2        = (const float*)d_in[14];
  const float* gw3        = (const float*)d_in[15];
  const float* gb3        = (const float*)d_in[16];
  float* out = (float*)d_out;

  float* out0 = out;                 // x_seed
  float* out1 = out + S_ELEMS;       // x_gcn
  float* out2 = out + 2 * S_ELEMS;   // x_freq
  float* out4 = out + 4 * S_ELEMS;   // scratch (seed^T) -> x_complete (mlp)
  float* out6 = out + 7 * S_ELEMS;   // adjacency
  float2* filtT = (float2*)(out + 5 * S_ELEMS);  // scratch -> gate weights (mlp)

  fill_kernel<<<256, 256, 0, stream>>>(x_input, mask, out0, out4);
  adj_prep_kernel<<<6, 256, 0, stream>>>(node_emb, freq_re, freq_im, out6, filtT);
  gcn_kernel<<<1024, 256, 0, stream>>>(out0, out6, gcn_w1, gcn_b1, gcn_w2, gcn_b2, out1);
  fft_kernel<<<1024, 256, 0, stream>>>(out4, filtT, out2);
  mlp_kernel<<<8192, 256, 0, stream>>>(x_input, mask, rate_id, rate_table,
                                       gw1, gb1, gw2, gb2, gw3, gb3, out);
}